// Round 1
// baseline (1020.998 us; speedup 1.0000x reference)
//
#include <hip/hip_runtime.h>
#include <math.h>

#define N_NODES 100000
#define N_EDGES 500000

// Workspace layout (bytes):
//   deg : [0,        400000)          float[N]
//   cv  : [400000,   6800000)         float[N*16]  (node-major [N][16])
//   acc : [6800000,  6800016)         double (padded)
//   xT  : [6800016,  13200016)        float[N*16]  (node-major [N][16])
//   tp  : [13200016, 13700016)        uchar[E]
#define OFF_DEG 0
#define OFF_CV  400000
#define OFF_ACC 6800000
#define OFF_XT  6800016
#define OFF_TP  13200016
#define ZERO_BYTES 6800016  // deg + cv + acc in one memset

__global__ void k_deg_tp(const int* __restrict__ src, const int* __restrict__ dst,
                         const int* __restrict__ et, float* __restrict__ deg,
                         unsigned char* __restrict__ tp) {
    int e = blockIdx.x * blockDim.x + threadIdx.x;
    if (e >= N_EDGES) return;
    int s = src[e], d = dst[e];
    atomicAdd(&deg[d], 1.0f);
    tp[e] = (unsigned char)(et[s] * 8 + et[d]);
}

__global__ void k_xT(const float* __restrict__ reps, const float* __restrict__ deg,
                     float* __restrict__ xT) {
    int n = blockIdx.x * blockDim.x + threadIdx.x;
    if (n >= N_NODES) return;
    float dg = deg[n];
    float inv = dg > 0.0f ? (1.0f / sqrtf(dg)) : 0.0f;
    float v[16];
#pragma unroll
    for (int j = 0; j < 16; ++j) v[j] = reps[j * N_NODES + n] * inv;
    float4* out = (float4*)(xT + (size_t)n * 16);
#pragma unroll
    for (int j = 0; j < 4; ++j)
        out[j] = make_float4(v[4*j], v[4*j+1], v[4*j+2], v[4*j+3]);
}

#define EPT 4  // edges per thread

__global__ __launch_bounds__(256) void k_edges(
    const int* __restrict__ src, const int* __restrict__ dst,
    const unsigned char* __restrict__ tp, const float* __restrict__ rmg,
    const float* __restrict__ xT, float* __restrict__ cv) {
    __shared__ float rm[64 * 256];  // full restriction_maps: 64 KB
    for (int i = threadIdx.x; i < 4096; i += 256)
        ((float4*)rm)[i] = ((const float4*)rmg)[i];
    __syncthreads();

    int base = blockIdx.x * (256 * EPT);
    for (int k = 0; k < EPT; ++k) {
        int e = base + k * 256 + (int)threadIdx.x;
        if (e >= N_EDGES) break;  // e is monotone in k per-thread

        int s = src[e], d = dst[e];
        const float4* xsp = (const float4*)(xT + (size_t)s * 16);
        const float4* xdp = (const float4*)(xT + (size_t)d * 16);
        float xs[16], xd[16];
#pragma unroll
        for (int j = 0; j < 4; ++j) {
            float4 a4 = xsp[j];
            xs[4*j] = a4.x; xs[4*j+1] = a4.y; xs[4*j+2] = a4.z; xs[4*j+3] = a4.w;
            float4 b4 = xdp[j];
            xd[4*j] = b4.x; xd[4*j+1] = b4.y; xd[4*j+2] = b4.z; xd[4*j+3] = b4.w;
        }

        float h[16], tl[16];
#pragma unroll
        for (int i = 0; i < 16; ++i) { h[i] = 0.0f; tl[i] = 0.0f; }

        int E4 = e >> 4;
        int b = e & 15;
        // head_maps[i,j,e] = RM[tp[e2]][a][b]; tail = swapped type pair, same (e2,a,b)
        // e2 = 1953*q + ((2q+E4)>>4), a = (2q+E4)&15, b = e&15   (q = i*16+j)
#pragma unroll
        for (int i = 0; i < 16; ++i) {
#pragma unroll
            for (int j = 0; j < 16; ++j) {
                int q = i * 16 + j;
                int u = 2 * q + E4;
                int a = u & 15;
                int e2 = 1953 * q + (u >> 4);
                int t = tp[e2];
                int tr = ((t & 7) << 3) | (t >> 3);
                int rowoff = (a << 4) + b;
                h[i]  += rm[(t  << 8) + rowoff] * xs[j];
                tl[i] += rm[(tr << 8) + rowoff] * xd[j];
            }
        }

        float* cvs = cv + (size_t)s * 16;
        float* cvd = cv + (size_t)d * 16;
#pragma unroll
        for (int i = 0; i < 16; ++i) {
            atomicAdd(&cvs[i], h[i]);
            atomicAdd(&cvd[i], -tl[i]);
        }
    }
}

__global__ void k_sumsq(const float* __restrict__ cv, double* __restrict__ acc) {
    int idx = blockIdx.x * blockDim.x + threadIdx.x;
    int stride = gridDim.x * blockDim.x;
    const int total4 = (16 * N_NODES) / 4;  // 400000 float4s
    double p = 0.0;
    for (int i = idx; i < total4; i += stride) {
        float4 v = ((const float4*)cv)[i];
        p += (double)v.x * v.x + (double)v.y * v.y
           + (double)v.z * v.z + (double)v.w * v.w;
    }
#pragma unroll
    for (int off = 32; off > 0; off >>= 1) p += __shfl_down(p, off, 64);
    __shared__ double sacc[4];
    int wid = threadIdx.x >> 6;
    if ((threadIdx.x & 63) == 0) sacc[wid] = p;
    __syncthreads();
    if (threadIdx.x == 0) {
        double s2 = sacc[0] + sacc[1] + sacc[2] + sacc[3];
        atomicAdd(acc, s2);
    }
}

__global__ void k_out(const double* __restrict__ acc, float* __restrict__ out) {
    out[0] = (float)acc[0];
}

extern "C" void kernel_launch(void* const* d_in, const int* in_sizes, int n_in,
                              void* d_out, int out_size, void* d_ws, size_t ws_size,
                              hipStream_t stream) {
    const float* reps = (const float*)d_in[0];          // [16, N]
    const float* rmg  = (const float*)d_in[1];          // [8,8,16,16]
    const int*   eidx = (const int*)d_in[2];            // [2, E]
    const int*   et   = (const int*)d_in[3];            // [N]
    const int* src = eidx;
    const int* dst = eidx + N_EDGES;

    char* ws = (char*)d_ws;
    float*         deg = (float*)(ws + OFF_DEG);
    float*         cv  = (float*)(ws + OFF_CV);
    double*        acc = (double*)(ws + OFF_ACC);
    float*         xT  = (float*)(ws + OFF_XT);
    unsigned char* tp  = (unsigned char*)(ws + OFF_TP);

    hipMemsetAsync(ws, 0, ZERO_BYTES, stream);

    k_deg_tp<<<(N_EDGES + 255) / 256, 256, 0, stream>>>(src, dst, et, deg, tp);
    k_xT<<<(N_NODES + 255) / 256, 256, 0, stream>>>(reps, deg, xT);
    k_edges<<<(N_EDGES + 256 * EPT - 1) / (256 * EPT), 256, 0, stream>>>(
        src, dst, tp, rmg, xT, cv);
    k_sumsq<<<1024, 256, 0, stream>>>(cv, acc);
    k_out<<<1, 1, 0, stream>>>(acc, (float*)d_out);
}

// Round 2
// 788.676 us; speedup vs baseline: 1.2946x; 1.2946x over previous
//
#include <hip/hip_runtime.h>
#include <math.h>

#define N_NODES 100000
#define N_EDGES 500000
#define N_E4    125000   // N_EDGES/4
#define NSEG    4
#define SEG4    31250    // int4s per segment

// ownership-scan params
#define CHUNK   392      // nodes per block; 256*392 = 100352 >= 100000
#define NBLK    256
#define T       512
#define QH_CAP  1024     // expected ~490 pushes/segment (Poisson, 22 sigma margin)
#define QT_CAP  1024

// Workspace layout (bytes):
//   deg : [0,       400000)    float[N]
//   acc : [400000,  400016)    double
//   xT  : [400016,  6800016)   float[N][16]
//   tp  : [6800016, 7300016)   uchar[E]
#define OFF_DEG 0
#define OFF_ACC 400000
#define OFF_XT  400016
#define OFF_TP  6800016
#define ZERO_BYTES 400016

__global__ void k_deg_tp(const int* __restrict__ src, const int* __restrict__ dst,
                         const int* __restrict__ et, float* __restrict__ deg,
                         unsigned char* __restrict__ tp) {
    int e = blockIdx.x * blockDim.x + threadIdx.x;
    if (e >= N_EDGES) return;
    int s = src[e], d = dst[e];
    atomicAdd(&deg[d], 1.0f);
    tp[e] = (unsigned char)(et[s] * 8 + et[d]);
}

__global__ void k_xT(const float* __restrict__ reps, const float* __restrict__ deg,
                     float* __restrict__ xT) {
    int n = blockIdx.x * blockDim.x + threadIdx.x;
    if (n >= N_NODES) return;
    float dg = deg[n];
    float inv = dg > 0.0f ? (1.0f / sqrtf(dg)) : 0.0f;
    float v[16];
#pragma unroll
    for (int j = 0; j < 16; ++j) v[j] = reps[j * N_NODES + n] * inv;
    float4* out = (float4*)(xT + (size_t)n * 16);
#pragma unroll
    for (int j = 0; j < 4; ++j)
        out[j] = make_float4(v[4*j], v[4*j+1], v[4*j+2], v[4*j+3]);
}

// head_maps[i,j,e] = RM[tp[e2]][a][b]   (raw reshape (E,16,16)->(16,16,E))
//   q = i*16+j; b = e&15; u = 2q + (e>>4); a = u&15; e2 = 1953*q + (u>>4)
// tail: same (e2,a,b), type pair swapped; input x[dst[e]]; sign -.
template<int ROLE>
__device__ __forceinline__ void proc_inc(int code,
                                         const unsigned char* __restrict__ tp,
                                         const float* __restrict__ rm,
                                         const float* __restrict__ xT,
                                         float* __restrict__ cvs, int base) {
    int e  = code & 0x7FFFF;
    int ln = code >> 19;
    const float4* xp = (const float4*)(xT + (size_t)(base + ln) * 16);
    float x[16];
#pragma unroll
    for (int j4 = 0; j4 < 4; ++j4) {
        float4 v = xp[j4];
        x[4*j4] = v.x; x[4*j4+1] = v.y; x[4*j4+2] = v.z; x[4*j4+3] = v.w;
    }
    int E4 = e >> 4, b = e & 15;
    float h[16];
#pragma unroll
    for (int i = 0; i < 16; ++i) h[i] = 0.0f;
#pragma unroll
    for (int i = 0; i < 16; ++i) {
#pragma unroll
        for (int j = 0; j < 16; ++j) {
            const int q = i * 16 + j;          // compile-time
            int u  = 2 * q + E4;
            int a  = u & 15;
            int e2 = 1953 * q + (u >> 4);
            int t  = tp[e2];
            if (ROLE) t = ((t & 7) << 3) | (t >> 3);
            h[i] += rm[(t << 8) + (a << 4) + b] * x[j];
        }
    }
    float* c = cvs + ln * 16;
#pragma unroll
    for (int i = 0; i < 16; ++i)
        atomicAdd(&c[i], ROLE ? -h[i] : h[i]);   // ds_add_f32, block-local
}

__global__ __launch_bounds__(T) void k_scan(
    const int* __restrict__ src, const int* __restrict__ dst,
    const unsigned char* __restrict__ tp, const float* __restrict__ rmg,
    const float* __restrict__ xT, double* __restrict__ acc) {
    extern __shared__ int dyn[];
    float* rm  = (float*)dyn;                 // 16384 f = 64KB
    float* cvs = rm + 16384;                  // CHUNK*16 f = 24.5KB
    int*   qH  = (int*)(cvs + CHUNK * 16);    // 4KB
    int*   qT  = qH + QH_CAP;                 // 4KB
    __shared__ int sQh, sQt;
    __shared__ double red[8];

    for (int i = threadIdx.x; i < 4096; i += T)
        ((float4*)rm)[i] = ((const float4*)rmg)[i];
    for (int i = threadIdx.x; i < CHUNK * 16; i += T) cvs[i] = 0.0f;
    if (threadIdx.x == 0) { sQh = 0; sQt = 0; }
    __syncthreads();

    const int base = blockIdx.x * CHUNK;
    const int4* src4 = (const int4*)src;
    const int4* dst4 = (const int4*)dst;

    for (int seg = 0; seg < NSEG; ++seg) {
        int lo = seg * SEG4, hi = lo + SEG4;
        for (int i4 = lo + (int)threadIdx.x; i4 < hi; i4 += T) {
            int4 s4 = src4[i4];
            int4 d4 = dst4[i4];
            int ebase = i4 * 4;
#pragma unroll
            for (int k = 0; k < 4; ++k) {
                int s = (k == 0) ? s4.x : (k == 1) ? s4.y : (k == 2) ? s4.z : s4.w;
                int d = (k == 0) ? d4.x : (k == 1) ? d4.y : (k == 2) ? d4.z : d4.w;
                unsigned ls = (unsigned)(s - base);
                unsigned ld = (unsigned)(d - base);
                if (ls < CHUNK) {
                    int p = atomicAdd(&sQh, 1);
                    if (p < QH_CAP) qH[p] = (int)((ls << 19) | (unsigned)(ebase + k));
                }
                if (ld < CHUNK) {
                    int p = atomicAdd(&sQt, 1);
                    if (p < QT_CAP) qT[p] = (int)((ld << 19) | (unsigned)(ebase + k));
                }
            }
        }
        __syncthreads();
        int nh = min(sQh, QH_CAP), nt = min(sQt, QT_CAP);
        for (int i = threadIdx.x; i < nh; i += T) proc_inc<0>(qH[i], tp, rm, xT, cvs, base);
        for (int i = threadIdx.x; i < nt; i += T) proc_inc<1>(qT[i], tp, rm, xT, cvs, base);
        __syncthreads();
        if (threadIdx.x == 0) { sQh = 0; sQt = 0; }
        __syncthreads();
    }

    // block-local sum of squares -> one f64 atomic per block
    double p = 0.0;
    for (int i = threadIdx.x; i < CHUNK * 16; i += T) {
        float v = cvs[i];
        p += (double)v * v;
    }
#pragma unroll
    for (int off = 32; off > 0; off >>= 1) p += __shfl_down(p, off, 64);
    int w = threadIdx.x >> 6;
    if ((threadIdx.x & 63) == 0) red[w] = p;
    __syncthreads();
    if (threadIdx.x == 0) {
        double t2 = 0.0;
#pragma unroll
        for (int i = 0; i < 8; ++i) t2 += red[i];
        atomicAdd(acc, t2);
    }
}

__global__ void k_out(const double* __restrict__ acc, float* __restrict__ out) {
    out[0] = (float)acc[0];
}

extern "C" void kernel_launch(void* const* d_in, const int* in_sizes, int n_in,
                              void* d_out, int out_size, void* d_ws, size_t ws_size,
                              hipStream_t stream) {
    const float* reps = (const float*)d_in[0];   // [16, N]
    const float* rmg  = (const float*)d_in[1];   // [8,8,16,16]
    const int*   eidx = (const int*)d_in[2];     // [2, E]
    const int*   et   = (const int*)d_in[3];     // [N]
    const int* src = eidx;
    const int* dst = eidx + N_EDGES;

    char* ws = (char*)d_ws;
    float*         deg = (float*)(ws + OFF_DEG);
    double*        acc = (double*)(ws + OFF_ACC);
    float*         xT  = (float*)(ws + OFF_XT);
    unsigned char* tp  = (unsigned char*)(ws + OFF_TP);

    hipMemsetAsync(ws, 0, ZERO_BYTES, stream);

    k_deg_tp<<<(N_EDGES + 255) / 256, 256, 0, stream>>>(src, dst, et, deg, tp);
    k_xT<<<(N_NODES + 255) / 256, 256, 0, stream>>>(reps, deg, xT);

    const int dynbytes = (16384 + CHUNK * 16) * 4 + (QH_CAP + QT_CAP) * 4;  // 98816 B
    static bool attr_set = []() {
        hipFuncSetAttribute(reinterpret_cast<const void*>(k_scan),
                            hipFuncAttributeMaxDynamicSharedMemorySize, 131072);
        return true;
    }();
    (void)attr_set;
    k_scan<<<NBLK, T, dynbytes, stream>>>(src, dst, tp, rmg, xT, acc);

    k_out<<<1, 1, 0, stream>>>(acc, (float*)d_out);
}

// Round 3
// 365.450 us; speedup vs baseline: 2.7938x; 2.1581x over previous
//
#include <hip/hip_runtime.h>
#include <math.h>

#define N_NODES 100000
#define N_EDGES 500000
#define NSEG    4
#define SEG4    31250    // int4s per segment of the edge scan

#define CHUNK   392      // nodes per block; 256*392 = 100352 >= 100000
#define NBLK    256
#define T       1024
#define QH_CAP  1024     // expected ~490 pushes/segment
#define QT_CAP  1024
#define NTBL    8000000  // 31250 * 256

// Workspace layout (bytes):
#define OFF_DEG 0         // float[N]      400000
#define OFF_ACC 400000    // double        16
#define OFF_XT  400016    // float[N][16]  6400000
#define OFF_TP  6800016   // uchar[E]      500000
#define OFF_TBL 7300016   // uchar[8M]     8000000   (total ~15.3MB)
#define ZERO_BYTES 400016

__global__ void k_deg_tp(const int* __restrict__ src, const int* __restrict__ dst,
                         const int* __restrict__ et, float* __restrict__ deg,
                         unsigned char* __restrict__ tp) {
    int e = blockIdx.x * blockDim.x + threadIdx.x;
    if (e >= N_EDGES) return;
    int s = src[e], d = dst[e];
    atomicAdd(&deg[d], 1.0f);
    tp[e] = (unsigned char)(et[s] * 8 + et[d]);
}

__global__ void k_xT(const float* __restrict__ reps, const float* __restrict__ deg,
                     float* __restrict__ xT) {
    int n = blockIdx.x * blockDim.x + threadIdx.x;
    if (n >= N_NODES) return;
    float dg = deg[n];
    float inv = dg > 0.0f ? (1.0f / sqrtf(dg)) : 0.0f;
    float v[16];
#pragma unroll
    for (int j = 0; j < 16; ++j) v[j] = reps[j * N_NODES + n] * inv;
    float4* out = (float4*)(xT + (size_t)n * 16);
#pragma unroll
    for (int j = 0; j < 4; ++j)
        out[j] = make_float4(v[4*j], v[4*j+1], v[4*j+2], v[4*j+3]);
}

// tbl[E4][q] = tp[e2(q,E4)]:  u = 2q+E4; e2 = 1953q + (u>>4)
__global__ __launch_bounds__(256) void k_tbl(const unsigned char* __restrict__ tp,
                                             unsigned char* __restrict__ tbl) {
    int idx = blockIdx.x * 256 + (int)threadIdx.x;
    if (idx >= NTBL) return;
    int E4 = idx >> 8, q = idx & 255;
    int u = 2 * q + E4;
    int e2 = 1953 * q + (u >> 4);
    tbl[idx] = tp[e2];
}

// head_maps[i,j,e] = RM[t(e2)][a][b], q=16i+j, b=e&15, a=(2j+E4)&15 (indep of i!),
// e2 dep only on (q, E4=e>>4)  -> t streamed from tbl row [E4][0..255].
// tail: swapped type pair, input x[dst], sign -.
template<int ROLE>
__device__ __forceinline__ void proc_inc(int code,
                                         const unsigned char* __restrict__ tbl,
                                         const float* __restrict__ rm,
                                         const float* __restrict__ xT,
                                         float* __restrict__ cvs, int base) {
    int e  = code & 0x7FFFF;
    int ln = code >> 19;
    const float4* xp = (const float4*)(xT + (size_t)(base + ln) * 16);
    float xs[16];
#pragma unroll
    for (int j4 = 0; j4 < 4; ++j4) {
        float4 v = xp[j4];
        xs[4*j4] = v.x; xs[4*j4+1] = v.y; xs[4*j4+2] = v.z; xs[4*j4+3] = v.w;
    }
    const int E4 = e >> 4, b = e & 15, c = E4 & 15;
    int aoff[16];
#pragma unroll
    for (int j = 0; j < 16; ++j)
        aoff[j] = ((((c + 2 * j) & 15) << 4) | b);

    const uint4* trow = (const uint4*)(tbl + (size_t)E4 * 256);
    float* cv = cvs + ln * 16;
#pragma unroll
    for (int k = 0; k < 16; ++k) {
        uint4 tv = trow[k];
        unsigned w[4] = {tv.x, tv.y, tv.z, tv.w};
        float acc = 0.0f;
#pragma unroll
        for (int j = 0; j < 16; ++j) {
            int t = (int)((w[j >> 2] >> ((j & 3) * 8)) & 255u);
            if (ROLE) t = ((t & 7) << 3) | (t >> 3);
            acc += rm[(t << 8) + aoff[j]] * xs[j];
        }
        atomicAdd(&cv[k], ROLE ? -acc : acc);   // ds_add_f32, block-local
    }
}

__global__ __launch_bounds__(T) void k_scan(
    const int* __restrict__ src, const int* __restrict__ dst,
    const unsigned char* __restrict__ tbl, const float* __restrict__ rmg,
    const float* __restrict__ xT, double* __restrict__ acc) {
    extern __shared__ int dyn[];
    float* rm  = (float*)dyn;                 // 16384 f = 64KB
    float* cvs = rm + 16384;                  // CHUNK*16 f = 24.5KB
    int*   qH  = (int*)(cvs + CHUNK * 16);    // 4KB
    int*   qT  = qH + QH_CAP;                 // 4KB
    __shared__ int sQh, sQt;
    __shared__ double red[16];

    for (int i = threadIdx.x; i < 4096; i += T)
        ((float4*)rm)[i] = ((const float4*)rmg)[i];
    for (int i = threadIdx.x; i < CHUNK * 16; i += T) cvs[i] = 0.0f;
    if (threadIdx.x == 0) { sQh = 0; sQt = 0; }
    __syncthreads();

    const int base = blockIdx.x * CHUNK;
    const int4* src4 = (const int4*)src;
    const int4* dst4 = (const int4*)dst;

    for (int seg = 0; seg < NSEG; ++seg) {
        int lo = seg * SEG4, hi = lo + SEG4;
        for (int i4 = lo + (int)threadIdx.x; i4 < hi; i4 += T) {
            int4 s4 = src4[i4];
            int4 d4 = dst4[i4];
            int ebase = i4 * 4;
#pragma unroll
            for (int k = 0; k < 4; ++k) {
                int s = (k == 0) ? s4.x : (k == 1) ? s4.y : (k == 2) ? s4.z : s4.w;
                int d = (k == 0) ? d4.x : (k == 1) ? d4.y : (k == 2) ? d4.z : d4.w;
                unsigned ls = (unsigned)(s - base);
                unsigned ld = (unsigned)(d - base);
                if (ls < CHUNK) {
                    int p = atomicAdd(&sQh, 1);
                    if (p < QH_CAP) qH[p] = (int)((ls << 19) | (unsigned)(ebase + k));
                }
                if (ld < CHUNK) {
                    int p = atomicAdd(&sQt, 1);
                    if (p < QT_CAP) qT[p] = (int)((ld << 19) | (unsigned)(ebase + k));
                }
            }
        }
        __syncthreads();
        int nh = min(sQh, QH_CAP), nt = min(sQt, QT_CAP);
        for (int i = threadIdx.x; i < nh; i += T) proc_inc<0>(qH[i], tbl, rm, xT, cvs, base);
        for (int i = threadIdx.x; i < nt; i += T) proc_inc<1>(qT[i], tbl, rm, xT, cvs, base);
        __syncthreads();
        if (threadIdx.x == 0) { sQh = 0; sQt = 0; }
        __syncthreads();
    }

    // block-local sum of squares -> one f64 atomic per block
    double p = 0.0;
    for (int i = threadIdx.x; i < CHUNK * 16; i += T) {
        float v = cvs[i];
        p += (double)v * v;
    }
#pragma unroll
    for (int off = 32; off > 0; off >>= 1) p += __shfl_down(p, off, 64);
    int w = threadIdx.x >> 6;
    if ((threadIdx.x & 63) == 0) red[w] = p;
    __syncthreads();
    if (threadIdx.x == 0) {
        double t2 = 0.0;
#pragma unroll
        for (int i = 0; i < 16; ++i) t2 += red[i];
        atomicAdd(acc, t2);
    }
}

__global__ void k_out(const double* __restrict__ acc, float* __restrict__ out) {
    out[0] = (float)acc[0];
}

extern "C" void kernel_launch(void* const* d_in, const int* in_sizes, int n_in,
                              void* d_out, int out_size, void* d_ws, size_t ws_size,
                              hipStream_t stream) {
    const float* reps = (const float*)d_in[0];   // [16, N]
    const float* rmg  = (const float*)d_in[1];   // [8,8,16,16]
    const int*   eidx = (const int*)d_in[2];     // [2, E]
    const int*   et   = (const int*)d_in[3];     // [N]
    const int* src = eidx;
    const int* dst = eidx + N_EDGES;

    char* ws = (char*)d_ws;
    float*         deg = (float*)(ws + OFF_DEG);
    double*        acc = (double*)(ws + OFF_ACC);
    float*         xT  = (float*)(ws + OFF_XT);
    unsigned char* tp  = (unsigned char*)(ws + OFF_TP);
    unsigned char* tbl = (unsigned char*)(ws + OFF_TBL);

    hipMemsetAsync(ws, 0, ZERO_BYTES, stream);

    k_deg_tp<<<(N_EDGES + 255) / 256, 256, 0, stream>>>(src, dst, et, deg, tp);
    k_xT<<<(N_NODES + 255) / 256, 256, 0, stream>>>(reps, deg, xT);
    k_tbl<<<NTBL / 256, 256, 0, stream>>>(tp, tbl);

    const int dynbytes = (16384 + CHUNK * 16) * 4 + (QH_CAP + QT_CAP) * 4;  // 98816 B
    static bool attr_set = []() {
        hipFuncSetAttribute(reinterpret_cast<const void*>(k_scan),
                            hipFuncAttributeMaxDynamicSharedMemorySize, 131072);
        return true;
    }();
    (void)attr_set;
    k_scan<<<NBLK, T, dynbytes, stream>>>(src, dst, tbl, rmg, xT, acc);

    k_out<<<1, 1, 0, stream>>>(acc, (float*)d_out);
}

// Round 6
// 272.135 us; speedup vs baseline: 3.7518x; 1.3429x over previous
//
#include <hip/hip_runtime.h>
#include <math.h>

#define N_NODES 100000
#define N_EDGES 500000
#define NGRP    31250        // N_EDGES/16
#define NTBL    8000000      // NGRP * 256

#define CHUNK   400          // nodes per owner block
#define NOWN    250          // 250*400 = 100000 exactly

// Workspace layout (bytes):
#define OFF_ACC   0          // double
#define OFF_GCNT  16         // uint[250]
#define OFF_QBASE 1024       // uint[251]
#define OFF_QCUR  2048       // uint[250]
#define OFF_CV    4096       // float[N][16]  6.4MB
#define OFF_TP    6404096    // uchar[E]
#define OFF_XT    6904096    // float[N][16]  6.4MB
#define OFF_TBL   13304096   // uchar[8M]
#define OFF_GQ    21304096   // uint[1M]      4MB
#define OFF_EMB   25304096   // float emb chunks (rest of ws)
#define ZERO_BYTES 6404096   // acc + gcnt + cv

__device__ __forceinline__ unsigned owner_of(int n) {
    // floor(n/400) = floor((n>>4)/25); magic /25
    return (unsigned)(((unsigned long long)((unsigned)n >> 4) * 1374389535ull) >> 35);
}

// ---- pass 1: per-owner incidence histogram (+ tp bytes) ----
__global__ __launch_bounds__(1024) void k_hist(
    const int* __restrict__ src, const int* __restrict__ dst,
    const int* __restrict__ et, unsigned char* __restrict__ tp,
    unsigned* __restrict__ gcnt) {
    __shared__ unsigned hist[NOWN];
    for (int i = threadIdx.x; i < NOWN; i += 1024) hist[i] = 0;
    __syncthreads();
    int base = blockIdx.x * 2048;
#pragma unroll
    for (int k = 0; k < 2; ++k) {
        int e = base + k * 1024 + (int)threadIdx.x;
        if (e < N_EDGES) {
            int s = src[e], d = dst[e];
            tp[e] = (unsigned char)(et[s] * 8 + et[d]);
            atomicAdd(&hist[owner_of(s)], 1u);
            atomicAdd(&hist[owner_of(d)], 1u);
        }
    }
    __syncthreads();
    for (int i = threadIdx.x; i < NOWN; i += 1024)
        if (hist[i]) atomicAdd(&gcnt[i], hist[i]);
}

// ---- exclusive prefix over 250 counts ----
__global__ void k_prefix(const unsigned* __restrict__ gcnt,
                         unsigned* __restrict__ qbase, unsigned* __restrict__ qcur) {
    __shared__ unsigned v[256];
    int t = threadIdx.x;
    v[t] = (t < NOWN) ? gcnt[t] : 0u;
    __syncthreads();
    unsigned my = v[t];
#pragma unroll
    for (int off = 1; off < 256; off <<= 1) {
        unsigned add = (t >= off) ? v[t - off] : 0u;
        __syncthreads();
        v[t] += add;
        __syncthreads();
    }
    if (t < NOWN) {
        unsigned excl = v[t] - my;
        qbase[t] = excl; qcur[t] = excl;
    }
    if (t == NOWN) qbase[NOWN] = v[NOWN - 1];
}

// ---- pass 2: place incidences into per-owner queue ranges ----
__global__ __launch_bounds__(1024) void k_place(
    const int* __restrict__ src, const int* __restrict__ dst,
    unsigned* __restrict__ qcur, unsigned* __restrict__ gq) {
    __shared__ unsigned hist[NOWN];
    __shared__ unsigned lcur[NOWN];
    for (int i = threadIdx.x; i < NOWN; i += 1024) hist[i] = 0;
    __syncthreads();
    int base = blockIdx.x * 2048;
#pragma unroll
    for (int k = 0; k < 2; ++k) {
        int e = base + k * 1024 + (int)threadIdx.x;
        if (e < N_EDGES) {
            atomicAdd(&hist[owner_of(src[e])], 1u);
            atomicAdd(&hist[owner_of(dst[e])], 1u);
        }
    }
    __syncthreads();
    for (int i = threadIdx.x; i < NOWN; i += 1024)
        lcur[i] = hist[i] ? atomicAdd(&qcur[i], hist[i]) : 0u;
    __syncthreads();
#pragma unroll
    for (int k = 0; k < 2; ++k) {
        int e = base + k * 1024 + (int)threadIdx.x;
        if (e < N_EDGES) {
            int s = src[e], d = dst[e];
            unsigned os = owner_of(s), od = owner_of(d);
            unsigned ps = atomicAdd(&lcur[os], 1u);
            gq[ps] = (unsigned)e | ((unsigned)(s - (int)os * CHUNK) << 19);
            unsigned pd = atomicAdd(&lcur[od], 1u);
            gq[pd] = (unsigned)e | ((unsigned)(d - (int)od * CHUNK) << 19) | (1u << 28);
        }
    }
}

// ---- per-owner: deg from tail entries, then xT = reps * deg^-1/2 ----
__global__ __launch_bounds__(1024) void k_degxT(
    const unsigned* __restrict__ qbase, const unsigned* __restrict__ gq,
    const float* __restrict__ reps, float* __restrict__ xT) {
    __shared__ unsigned dh[CHUNK];
    for (int i = threadIdx.x; i < CHUNK; i += 1024) dh[i] = 0;
    __syncthreads();
    int o = blockIdx.x;
    unsigned lo = qbase[o], hi = qbase[o + 1];
    for (unsigned i = lo + threadIdx.x; i < hi; i += 1024) {
        unsigned ent = gq[i];
        if (ent >> 28) atomicAdd(&dh[(ent >> 19) & 511u], 1u);
    }
    __syncthreads();
    int nbase = o * CHUNK;
    for (int idx = threadIdx.x; idx < CHUNK; idx += 1024) {
        int n = nbase + idx;
        unsigned dg = dh[idx];
        float inv = dg ? 1.0f / sqrtf((float)dg) : 0.0f;
        float v[16];
#pragma unroll
        for (int j = 0; j < 16; ++j) v[j] = reps[j * N_NODES + n] * inv;
        float4* outp = (float4*)(xT + (size_t)n * 16);
#pragma unroll
        for (int j4 = 0; j4 < 4; ++j4)
            outp[j4] = make_float4(v[4*j4], v[4*j4+1], v[4*j4+2], v[4*j4+3]);
    }
}

// ---- tbl[E4][q] = tp[e2(q,E4)]:  u = 2q+E4; e2 = 1953q + (u>>4) ----
__global__ __launch_bounds__(256) void k_tbl(const unsigned char* __restrict__ tp,
                                             unsigned char* __restrict__ tbl) {
    int idx = blockIdx.x * 256 + (int)threadIdx.x;
    int E4 = idx >> 8, q = idx & 255;
    int u = 2 * q + E4;
    int e2 = 1953 * q + (u >> 4);
    tbl[idx] = tp[e2];
}

// ---- wave-cooperative embedding for groups [g0, g0+ng) ----
// head_maps[i,j,e] = RM[t][a][b]; q=16i+j, b=e&15, a=(2j+grp)&15, t=tbl[grp][q]
// (tail: byte-swapped t, x from dst). Wave: lanes=(b, ig), lane's i = 4*ig+ip.
__global__ __launch_bounds__(1024) void k_emb(
    const int* __restrict__ src, const int* __restrict__ dst,
    const unsigned char* __restrict__ tbl, const float* __restrict__ rmg,
    const float* __restrict__ xT, float* __restrict__ emb,
    int g0, int ng, int ECe) {
    __shared__ float rm[16384];   // XOR-swizzled copy: dst = i ^ ((i>>8)&31)
    for (int i = threadIdx.x; i < 16384; i += 1024) {
        float v = rmg[i];
        rm[i ^ ((i >> 8) & 31)] = v;
    }
    __syncthreads();

    const int wid = threadIdx.x >> 6, lane = threadIdx.x & 63;
    const int b = lane & 15, ig = lane >> 4;
    const int ntask = ng * 2;

    for (int task = blockIdx.x * 16 + wid; task < ntask; task += 256 * 16) {
        const int lgrp = task >> 1, role = task & 1;
        const int grp = g0 + lgrp;
        const int e = grp * 16 + b;
        const int node = role ? dst[e] : src[e];

        float xs[16];
        const float4* xp = (const float4*)(xT + (size_t)node * 16);
#pragma unroll
        for (int j4 = 0; j4 < 4; ++j4) {
            float4 v = xp[j4];
            xs[4*j4] = v.x; xs[4*j4+1] = v.y; xs[4*j4+2] = v.z; xs[4*j4+3] = v.w;
        }

        unsigned w[16];
        const uint4* tr4 = (const uint4*)(tbl + (size_t)grp * 256 + ig * 64);
#pragma unroll
        for (int ip = 0; ip < 4; ++ip) {
            uint4 u = tr4[ip];
            w[ip*4+0] = u.x; w[ip*4+1] = u.y; w[ip*4+2] = u.z; w[ip*4+3] = u.w;
        }
        if (role) {   // byte-parallel type-pair swap: t' = ((t&7)<<3)|(t>>3)
#pragma unroll
            for (int c = 0; c < 16; ++c)
                w[c] = ((w[c] & 0x07070707u) << 3) | ((w[c] >> 3) & 0x07070707u);
        }

        unsigned vab[16];
#pragma unroll
        for (int jj = 0; jj < 16; ++jj)
            vab[jj] = ((unsigned)((2 * jj + grp) & 15) << 4) | (unsigned)b;

        float h0 = 0.f, h1 = 0.f, h2 = 0.f, h3 = 0.f;
#pragma unroll
        for (int ip = 0; ip < 4; ++ip) {
            float hacc = 0.f;
#pragma unroll
            for (int jj = 0; jj < 16; ++jj) {
                unsigned t = (w[ip*4 + (jj >> 2)] >> ((jj & 3) * 8)) & 255u;
                unsigned idx = ((t << 8) + vab[jj]) ^ (t & 31u);
                hacc += rm[idx] * xs[jj];
            }
            if (ip == 0) h0 = hacc; else if (ip == 1) h1 = hacc;
            else if (ip == 2) h2 = hacc; else h3 = hacc;
        }
        // lane covers i = 4*ig .. 4*ig+3 -> one float4
        const int le = lgrp * 16 + b;
        float4* op = (float4*)(emb + ((size_t)role * ECe + le) * 16);
        op[ig] = make_float4(h0, h1, h2, h3);
    }
}

// ---- per-owner gather-accumulate (edges in [elo, elo+cnt)), cv persistent ----
__global__ __launch_bounds__(1024) void k_acc(
    const unsigned* __restrict__ qbase, const unsigned* __restrict__ gq,
    const float* __restrict__ emb, float* __restrict__ cv,
    int elo, int cnt, int ECe) {
    __shared__ float cvs[CHUNK * 17];    // stride 17: conflict-free ds atomics
    int o = blockIdx.x;
    int nbase = o * CHUNK;
    for (int idx = threadIdx.x; idx < CHUNK * 16; idx += 1024)
        cvs[(idx >> 4) * 17 + (idx & 15)] = cv[nbase * 16 + idx];
    __syncthreads();
    unsigned lo = qbase[o], hi = qbase[o + 1];
    for (unsigned it = lo + threadIdx.x; it < hi; it += 1024) {
        unsigned ent = gq[it];
        unsigned e = ent & 0x7FFFFu;
        if ((unsigned)(e - (unsigned)elo) >= (unsigned)cnt) continue;
        unsigned ln = (ent >> 19) & 511u, role = ent >> 28;
        unsigned le = e - (unsigned)elo;
        const float4* ep = (const float4*)(emb + ((size_t)role * ECe + le) * 16);
        float sgn = role ? -1.0f : 1.0f;
        float* c = cvs + ln * 17;
#pragma unroll
        for (int k4 = 0; k4 < 4; ++k4) {
            float4 v = ep[k4];
            atomicAdd(&c[k4*4+0], sgn * v.x);
            atomicAdd(&c[k4*4+1], sgn * v.y);
            atomicAdd(&c[k4*4+2], sgn * v.z);
            atomicAdd(&c[k4*4+3], sgn * v.w);
        }
    }
    __syncthreads();
    for (int idx = threadIdx.x; idx < CHUNK * 16; idx += 1024)
        cv[nbase * 16 + idx] = cvs[(idx >> 4) * 17 + (idx & 15)];
}

// ---- sum of squares over cv ----
__global__ __launch_bounds__(256) void k_sq(const float* __restrict__ cv,
                                            double* __restrict__ acc) {
    __shared__ double red[4];
    int idx = blockIdx.x * 256 + (int)threadIdx.x;
    int stride = gridDim.x * 256;
    const int total4 = (16 * N_NODES) / 4;  // 400000
    double p = 0.0;
    for (int i = idx; i < total4; i += stride) {
        float4 v = ((const float4*)cv)[i];
        p += (double)v.x * v.x + (double)v.y * v.y
           + (double)v.z * v.z + (double)v.w * v.w;
    }
#pragma unroll
    for (int off = 32; off > 0; off >>= 1) p += __shfl_down(p, off, 64);
    int w = threadIdx.x >> 6;
    if ((threadIdx.x & 63) == 0) red[w] = p;
    __syncthreads();
    if (threadIdx.x == 0)
        atomicAdd(acc, red[0] + red[1] + red[2] + red[3]);
}

__global__ void k_out(const double* __restrict__ acc, float* __restrict__ out) {
    out[0] = (float)acc[0];
}

extern "C" void kernel_launch(void* const* d_in, const int* in_sizes, int n_in,
                              void* d_out, int out_size, void* d_ws, size_t ws_size,
                              hipStream_t stream) {
    const float* reps = (const float*)d_in[0];   // [16, N]
    const float* rmg  = (const float*)d_in[1];   // [8,8,16,16]
    const int*   eidx = (const int*)d_in[2];     // [2, E]
    const int*   et   = (const int*)d_in[3];     // [N]
    const int* src = eidx;
    const int* dst = eidx + N_EDGES;

    char* ws = (char*)d_ws;
    double*        acc   = (double*)(ws + OFF_ACC);
    unsigned*      gcnt  = (unsigned*)(ws + OFF_GCNT);
    unsigned*      qbase = (unsigned*)(ws + OFF_QBASE);
    unsigned*      qcur  = (unsigned*)(ws + OFF_QCUR);
    float*         cv    = (float*)(ws + OFF_CV);
    unsigned char* tp    = (unsigned char*)(ws + OFF_TP);
    float*         xT    = (float*)(ws + OFF_XT);
    unsigned char* tbl   = (unsigned char*)(ws + OFF_TBL);
    unsigned*      gq    = (unsigned*)(ws + OFF_GQ);
    float*         emb   = (float*)(ws + OFF_EMB);

    // emb chunking from available workspace (constant across calls).
    // One group of 16 edges needs 2 roles * 16 edges * 16 f * 4B = 2048 B.
    size_t avail = (ws_size > (size_t)OFF_EMB) ? ws_size - (size_t)OFF_EMB : 0;
    int ECg = (int)(avail / 2048);
    if (ECg < 1) ECg = 1;
    if (ECg > NGRP) ECg = NGRP;
    const int ECe = ECg * 16;

    hipMemsetAsync(ws, 0, ZERO_BYTES, stream);

    k_hist  <<<245, 1024, 0, stream>>>(src, dst, et, tp, gcnt);
    k_tbl   <<<NTBL / 256, 256, 0, stream>>>(tp, tbl);
    k_prefix<<<1, 256, 0, stream>>>(gcnt, qbase, qcur);
    k_place <<<245, 1024, 0, stream>>>(src, dst, qcur, gq);
    k_degxT <<<NOWN, 1024, 0, stream>>>(qbase, gq, reps, xT);

    for (int g0 = 0; g0 < NGRP; g0 += ECg) {
        int ng = (NGRP - g0 < ECg) ? (NGRP - g0) : ECg;
        k_emb<<<256, 1024, 0, stream>>>(src, dst, tbl, rmg, xT, emb, g0, ng, ECe);
        k_acc<<<NOWN, 1024, 0, stream>>>(qbase, gq, emb, cv, g0 * 16, ng * 16, ECe);
    }

    k_sq <<<256, 256, 0, stream>>>(cv, acc);
    k_out<<<1, 1, 0, stream>>>(acc, (float*)d_out);
}